// Round 6
// baseline (31427.505 us; speedup 1.0000x reference)
//
#include <hip/hip_runtime.h>
#include <hip/hip_fp16.h>

typedef unsigned short ushort_t;
typedef unsigned int uint_t;

#define BN 512
#define LN 1024
#define FN 38
#define HN 256
#define ZDN 4
#define FXN 64
#define FZN 32

#define NT 512
#define NWG 256

__device__ __forceinline__ ushort_t f2h(float f) { return __half_as_ushort(__float2half(f)); }
__device__ __forceinline__ float h2f(ushort_t u) { return __half2float(__ushort_as_half(u)); }
__device__ __forceinline__ uint_t pk2(float a, float b) {
    return (uint_t)f2h(a) | ((uint_t)f2h(b) << 16);
}

#if defined(__has_builtin)
#if __has_builtin(__builtin_amdgcn_fdot2)
#define HAVE_FDOT2 1
#endif
#endif

typedef _Float16 hv2 __attribute__((ext_vector_type(2)));

__device__ __forceinline__ float dot2h(uint_t w, uint_t a, float acc) {
#ifdef HAVE_FDOT2
    return __builtin_amdgcn_fdot2(__builtin_bit_cast(hv2, w), __builtin_bit_cast(hv2, a), acc, false);
#else
    return acc + h2f((ushort_t)w) * h2f((ushort_t)a)
               + h2f((ushort_t)(w >> 16)) * h2f((ushort_t)(a >> 16));
#endif
}

__device__ __forceinline__ float sigmoidf_(float v) { return 1.0f / (1.0f + expf(-v)); }
__device__ __forceinline__ float softplusf_(float v) {
    return fmaxf(v, 0.0f) + log1pf(expf(-fabsf(v)));
}

// Per-thread register slab, thread t: j2 = t>>1 (row j), kh = t&1 (k-half).
// act coords: [h(256) | fx(64) | fz(32)] = 352. Slices: r/z: [176kh,176kh+176);
// in: x-k [48kh,+48); units n: 0..43 r, 44..87 z, 88..99 in. uint layout [n][t][2].
__global__ __launch_bounds__(256) void repack_slab(const float* __restrict__ W_ih,
                                                   const float* __restrict__ W_hh,
                                                   uint_t* __restrict__ slab) {
    int uid = blockIdx.x * 256 + threadIdx.x;
    if (uid >= 100 * 1024) return;
    int n = uid >> 10, rem = uid & 1023, t = rem >> 1, hw = rem & 1;
    int j2 = t >> 1, kh = t & 1;
    float v0, v1;
    if (n < 88) {
        int g = (n < 44) ? 0 : 1;
        int ki = n - g * 44;
        int ak = 176 * kh + 4 * ki + 2 * hw;   // even; pair never crosses 256
        int row = g * 256 + j2;
        v0 = (ak < 256) ? W_hh[row * 256 + ak] : W_ih[row * 96 + (ak - 256)];
        v1 = (ak + 1 < 256) ? W_hh[row * 256 + ak + 1] : W_ih[row * 96 + (ak + 1 - 256)];
    } else {
        int ki = n - 88;
        int xk = 48 * kh + 4 * ki + 2 * hw;
        v0 = W_ih[(512 + j2) * 96 + xk];
        v1 = W_ih[(512 + j2) * 96 + xk + 1];
    }
    slab[uid] = pk2(v0, v1);
}

// hn-gate weights: whn_ws[row r][128 uints], uint u <-> k {2u, 2u+1}
__global__ __launch_bounds__(256) void repack_whn(const float* __restrict__ W_hh,
                                                  uint_t* __restrict__ whn_ws) {
    int uid = blockIdx.x * 256 + threadIdx.x;
    if (uid >= 256 * 128) return;
    int r = uid >> 7, u = uid & 127;
    whn_ws[uid] = pk2(W_hh[(512 + r) * 256 + 2 * u], W_hh[(512 + r) * 256 + 2 * u + 1]);
}

// phi weights f16: [c(0..3 loc, 4..7 scale)][160 uints]
__global__ __launch_bounds__(256) void repack_wp(const float* __restrict__ Wp_loc,
                                                 const float* __restrict__ Wp_scale,
                                                 uint_t* __restrict__ wpg) {
    int uid = blockIdx.x * 256 + threadIdx.x;
    if (uid >= 8 * 160) return;
    int c = uid / 160, u = uid % 160;
    const float* src = (c < 4) ? (Wp_loc + c * 320) : (Wp_scale + (c - 4) * 320);
    wpg[uid] = pk2(src[2 * u], src[2 * u + 1]);
}

// theta weights f16: [38][144 uints], k-order cat(fz, h) as in Wt_loc
__global__ __launch_bounds__(256) void repack_wt(const float* __restrict__ Wt_loc,
                                                 uint_t* __restrict__ wtg) {
    int uid = blockIdx.x * 256 + threadIdx.x;
    if (uid >= 38 * 144) return;
    wtg[uid] = pk2(Wt_loc[2 * uid], Wt_loc[2 * uid + 1]);
}

// fx = relu(x @ Wx^T + bx) for all (b,l), stored f16-packed [B][L][64].
__global__ __launch_bounds__(256) void fx_pre(const float* __restrict__ x,
                                              const float* __restrict__ Wx,
                                              const float* __restrict__ bx,
                                              ushort_t* __restrict__ fxbuf) {
    __shared__ float w[FXN][FN + 1];
    __shared__ float bxs[FXN];
    int t = threadIdx.x;
    for (int i = t; i < FXN * FN; i += 256) w[i / FN][i % FN] = Wx[i];
    if (t < FXN) bxs[t] = bx[t];
    __syncthreads();
    size_t id = (size_t)blockIdx.x * 256 + t;
    const float* xr = x + id * FN;
    float xv[FN];
#pragma unroll
    for (int f = 0; f < FN; ++f) xv[f] = xr[f];
    uint4* dst = (uint4*)(fxbuf + id * FXN);
#pragma unroll
    for (int e8 = 0; e8 < 8; ++e8) {
        float a[8];
#pragma unroll
        for (int u = 0; u < 8; ++u) {
            int e = e8 * 8 + u;
            float acc = bxs[e];
#pragma unroll
            for (int f = 0; f < FN; ++f) acc += xv[f] * w[e][f];
            a[u] = fmaxf(acc, 0.0f);
        }
        uint4 o;
        o.x = pk2(a[0], a[1]); o.y = pk2(a[2], a[3]);
        o.z = pk2(a[4], a[5]); o.w = pk2(a[6], a[7]);
        dst[e8] = o;
    }
}

#define RZ_STEP(i) { \
    uint4 x0 = A0[22 * kh + (i)]; \
    uint4 x1 = A1[22 * kh + (i)]; \
    uint2 wa = wr[2 * (i)], wb = wr[2 * (i) + 1]; \
    ar0 = dot2h(wa.x, x0.x, ar0); ar0 = dot2h(wa.y, x0.y, ar0); \
    ar0 = dot2h(wb.x, x0.z, ar0); ar0 = dot2h(wb.y, x0.w, ar0); \
    ar1 = dot2h(wa.x, x1.x, ar1); ar1 = dot2h(wa.y, x1.y, ar1); \
    ar1 = dot2h(wb.x, x1.z, ar1); ar1 = dot2h(wb.y, x1.w, ar1); \
    uint2 za = wz[2 * (i)], zb = wz[2 * (i) + 1]; \
    az0 = dot2h(za.x, x0.x, az0); az0 = dot2h(za.y, x0.y, az0); \
    az0 = dot2h(zb.x, x0.z, az0); az0 = dot2h(zb.y, x0.w, az0); \
    az1 = dot2h(za.x, x1.x, az1); az1 = dot2h(za.y, x1.y, az1); \
    az1 = dot2h(zb.x, x1.z, az1); az1 = dot2h(zb.y, x1.w, az1); }

template <bool FXPRE>
__global__ __launch_bounds__(NT, 2) void vrnn_main(
    const float* __restrict__ x, const float* __restrict__ eps,
    const float* __restrict__ Wx, const float* __restrict__ bx,
    const float* __restrict__ Wz1, const float* __restrict__ bz1,
    const float* __restrict__ Wz2, const float* __restrict__ bz2,
    const float* __restrict__ bp_loc, const float* __restrict__ bp_scale,
    const float* __restrict__ bt_loc,
    const float* __restrict__ b_ih, const float* __restrict__ b_hh,
    const uint_t* __restrict__ slab, const uint_t* __restrict__ whn_ws,
    const uint_t* __restrict__ wpg, const uint_t* __restrict__ wtg,
    const ushort_t* __restrict__ fxbuf,
    float* __restrict__ out)
{
    __shared__ uint_t whn[256 * 132];                  // hn weights, padded rows
    __shared__ uint_t wpH[8 * 160];                    // phi weights f16
    __shared__ __attribute__((aligned(16))) uint_t actp[2][2][176];  // f16 acts, dbuf
    __shared__ float pp[2][8][16];
    __shared__ float wz1s[16][ZDN];
    __shared__ float wz2s[FZN][16];
    __shared__ float bz1s[16], bz2s[FZN], btls[FN], bpls[ZDN], bpss[ZDN];
    __shared__ float epsb[2][ZDN];

    const int t = threadIdx.x;
    const int b0 = blockIdx.x * 2;
    const int j2 = t >> 1, kh = t & 1;

    // ---- one-time LDS init
    for (int i = t; i < 256 * 128; i += NT) whn[(i >> 7) * 132 + (i & 127)] = whn_ws[i];
    for (int i = t; i < 8 * 160; i += NT) wpH[i] = wpg[i];
    if (t < 64) ((float*)wz1s)[t] = Wz1[t];
    for (int i = t; i < FZN * 16; i += NT) ((float*)wz2s)[i] = Wz2[i];
    if (t < 16) bz1s[t] = bz1[t];
    if (t >= 32 && t < 64) bz2s[t - 32] = bz2[t - 32];
    if (t >= 64 && t < 64 + FN) btls[t - 64] = bt_loc[t - 64];
    if (t >= 128 && t < 132) bpls[t - 128] = bp_loc[t - 128];
    if (t >= 160 && t < 164) bpss[t - 160] = bp_scale[t - 160];
    // zero only h region of buffer 0 (everything else is written before read)
    if (t < 256) actp[0][t >> 7][t & 127] = 0u;
    if (t >= 448 && t < 456) {
        int m = (t >> 2) & 1, c = t & 3;
        epsb[m][c] = eps[(size_t)(b0 + m) * ZDN + c];
    }
    if (FXPRE && t >= 480 && t < 496) {
        int m = (t >> 3) & 1, p = t & 7;
        uint4 v = *(const uint4*)(fxbuf + ((size_t)(b0 + m) * LN) * FXN + p * 8);
        uint_t* d = &actp[0][m][128 + p * 4];
        d[0] = v.x; d[1] = v.y; d[2] = v.z; d[3] = v.w;
    }

    // ---- persistent register weights: 200 VGPRs
    const uint2* S2 = (const uint2*)slab;
    uint2 wr[44], wz[44], wi[12];
#pragma unroll
    for (int n = 0; n < 44; ++n) wr[n] = S2[n * 512 + t];
#pragma unroll
    for (int n = 0; n < 44; ++n) wz[n] = S2[(44 + n) * 512 + t];
#pragma unroll
    for (int n = 0; n < 12; ++n) wi[n] = S2[(88 + n) * 512 + t];

    const float bsr_o = b_ih[j2] + b_hh[j2];
    const float bsz_o = b_ih[HN + j2] + b_hh[HN + j2];
    const float bin_o = b_ih[2 * HN + j2];
    const float bhn_o = b_hh[2 * HN + j2];
    float h_own = 0.0f;          // h[m=kh][j2], f32, lives in a register

    __syncthreads();

#pragma unroll 1
    for (int l = 0; l < LN; ++l) {
        const int cur = l & 1, nxt = cur ^ 1;
        const uint_t* Au0 = actp[cur][0];
        const uint_t* Au1 = actp[cur][1];
        const uint4* A0 = (const uint4*)Au0;
        const uint4* A1 = (const uint4*)Au1;

        if (!FXPRE) {
            if (t < 64) {
                int m = t >> 5, e2 = t & 31;
                const float* xr = x + ((size_t)(b0 + m) * LN + l) * FN;
                float a0 = bx[2 * e2], a1 = bx[2 * e2 + 1];
                const float* w0 = Wx + (2 * e2) * FN;
                const float* w1 = w0 + FN;
#pragma unroll
                for (int f = 0; f < FN; ++f) { float xv = xr[f]; a0 += xv * w0[f]; a1 += xv * w1[f]; }
                actp[cur][m][128 + e2] = pk2(fmaxf(a0, 0.0f), fmaxf(a1, 0.0f));
            }
            if (t >= 64 && t < 72) {
                int m = (t >> 2) & 1, c = t & 3;
                epsb[m][c] = eps[((size_t)l * BN + b0 + m) * ZDN + c];
            }
            __syncthreads();
        }

        // prefetch next-step inputs (wave 7)
        float pf_eps = 0.0f;
        uint4 pf_fx = {0, 0, 0, 0};
        if (FXPRE) {
            int lp = (l + 1 < LN) ? l + 1 : LN - 1;
            if (t >= 448 && t < 456) {
                int m = (t >> 2) & 1, c = t & 3;
                pf_eps = eps[((size_t)lp * BN + b0 + m) * ZDN + c];
            }
            if (t >= 480 && t < 496) {
                int m = (t >> 3) & 1, p = t & 7;
                pf_fx = *(const uint4*)(fxbuf + ((size_t)(b0 + m) * LN + lp) * FXN + p * 8);
            }
        }

        // ---- B: phi partials (256 threads), f16 acts x f16 weights
        if (t < 256) {
            int m = t >> 7, r = t & 127, c = r >> 4, ks = r & 15;
            const uint2* wv = (const uint2*)&wpH[c * 160 + ks * 10];
            const uint2* av = (const uint2*)((m ? Au1 : Au0) + ks * 10);
            float acc = 0.0f;
#pragma unroll
            for (int i = 0; i < 5; ++i) {
                uint2 w = wv[i], a = av[i];
                acc = dot2h(w.x, a.x, acc); acc = dot2h(w.y, a.y, acc);
            }
            pp[m][c][ks] = acc;
        }
        __syncthreads();   // sync1: pp ready

        // ---- CDE (wave 0) overlapped with hn + r/z fz-free dots (all waves)
        if (t < 64) {
            int m = t >> 5, qq = t & 31;
            float zz[ZDN];
#pragma unroll
            for (int c = 0; c < ZDN; ++c) {
                float lo = bpls[c], sc = bpss[c];
#pragma unroll
                for (int ks = 0; ks < 16; ++ks) { lo += pp[m][c][ks]; sc += pp[m][c + 4][ks]; }
                zz[c] = lo + softplusf_(sc) * epsb[m][c];
            }
            float acc = bz2s[qq];
#pragma unroll
            for (int k = 0; k < 16; ++k) {
                float a = bz1s[k];
#pragma unroll
                for (int c = 0; c < ZDN; ++c) a += zz[c] * wz1s[k][c];
                acc += fmaxf(a, 0.0f) * wz2s[qq][k];
            }
            float v = fmaxf(acc, 0.0f);
            float oth = __shfl_xor(v, 1);
            if (!(qq & 1)) actp[cur][m][160 + (qq >> 1)] = pk2(v, oth);
        }

        // hn gate (pure h, LDS weights)
        float ah0 = 0.0f, ah1 = 0.0f;
        {
            const uint4* wh4 = (const uint4*)&whn[j2 * 132 + 64 * kh];
#pragma unroll
            for (int i = 0; i < 16; ++i) {
                uint4 w = wh4[i];
                uint4 x0 = A0[16 * kh + i];
                uint4 x1 = A1[16 * kh + i];
                ah0 = dot2h(w.x, x0.x, ah0); ah0 = dot2h(w.y, x0.y, ah0);
                ah0 = dot2h(w.z, x0.z, ah0); ah0 = dot2h(w.w, x0.w, ah0);
                ah1 = dot2h(w.x, x1.x, ah1); ah1 = dot2h(w.y, x1.y, ah1);
                ah1 = dot2h(w.z, x1.z, ah1); ah1 = dot2h(w.w, x1.w, ah1);
            }
        }
        // r/z dots, fz-independent part (kh=0: whole slice is h; kh=1: up to fx)
        float ar0 = 0, ar1 = 0, az0 = 0, az1 = 0;
#pragma unroll
        for (int i = 0; i < 18; ++i) RZ_STEP(i)
        if (kh == 0) {
#pragma unroll
            for (int i = 18; i < 22; ++i) RZ_STEP(i)
        }
        __syncthreads();   // sync2: fz ready

        if (kh == 1) {
#pragma unroll
            for (int i = 18; i < 22; ++i) RZ_STEP(i)
        }
        // in gate
        float ai0 = 0.0f, ai1 = 0.0f;
#pragma unroll
        for (int i = 0; i < 6; ++i) {
            uint4 x0 = A0[32 + 6 * kh + i];
            uint4 x1 = A1[32 + 6 * kh + i];
            uint2 wa = wi[2 * i], wb = wi[2 * i + 1];
            ai0 = dot2h(wa.x, x0.x, ai0); ai0 = dot2h(wa.y, x0.y, ai0);
            ai0 = dot2h(wb.x, x0.z, ai0); ai0 = dot2h(wb.y, x0.w, ai0);
            ai1 = dot2h(wa.x, x1.x, ai1); ai1 = dot2h(wa.y, x1.y, ai1);
            ai1 = dot2h(wb.x, x1.z, ai1); ai1 = dot2h(wb.y, x1.w, ai1);
        }

        // theta (weights streamed from L2-resident global)
        if (t < 304) {
            int o = t >> 2, s4 = t & 3, f = o >> 1, m = o & 1;
            const uint4* wt4 = ((const uint4*)wtg) + f * 36;
            const uint4* ap = m ? A1 : A0;
            float acc = 0.0f;
#pragma unroll
            for (int i2 = 0; i2 < 9; ++i2) {
                int i = s4 * 9 + i2;
                uint4 w = wt4[i];
                uint4 a = (i < 4) ? ap[40 + i] : ap[i - 4];   // fz | h
                acc = dot2h(w.x, a.x, acc); acc = dot2h(w.y, a.y, acc);
                acc = dot2h(w.z, a.z, acc); acc = dot2h(w.w, a.w, acc);
            }
            acc += __shfl_xor(acc, 1);
            acc += __shfl_xor(acc, 2);
            if (!s4) out[((size_t)(b0 + m) * LN + l) * FN + f] = acc + btls[f];
        }

        // combine k-halves (pair lanes) + gates + h update
        {
            float Tr0 = ar0 + __shfl_xor(ar0, 1);
            float Tr1 = ar1 + __shfl_xor(ar1, 1);
            float Tz0 = az0 + __shfl_xor(az0, 1);
            float Tz1 = az1 + __shfl_xor(az1, 1);
            float Ti0 = ai0 + __shfl_xor(ai0, 1);
            float Ti1 = ai1 + __shfl_xor(ai1, 1);
            float Th0 = ah0 + __shfl_xor(ah0, 1);
            float Th1 = ah1 + __shfl_xor(ah1, 1);
            float gr = kh ? Tr1 : Tr0;
            float gz = kh ? Tz1 : Tz0;
            float gi = kh ? Ti1 : Ti0;
            float gh = kh ? Th1 : Th0;
            float r_ = sigmoidf_(gr + bsr_o);
            float z_ = sigmoidf_(gz + bsz_o);
            float n_ = tanhf(gi + bin_o + r_ * (gh + bhn_o));
            float hnew = (1.0f - z_) * n_ + z_ * h_own;
            h_own = hnew;
            float hp = __shfl_xor(hnew, 2);
            if (!(t & 2)) actp[nxt][kh][j2 >> 1] = pk2(hnew, hp);
        }

        // park prefetched inputs into next buffer
        if (FXPRE) {
            if (t >= 448 && t < 456) { int m = (t >> 2) & 1, c = t & 3; epsb[m][c] = pf_eps; }
            if (t >= 480 && t < 496) {
                int m = (t >> 3) & 1, p = t & 7;
                uint_t* d = &actp[nxt][m][128 + p * 4];
                d[0] = pf_fx.x; d[1] = pf_fx.y; d[2] = pf_fx.z; d[3] = pf_fx.w;
            }
        }
        __syncthreads();   // sync3
    }
}

extern "C" void kernel_launch(void* const* d_in, const int* in_sizes, int n_in,
                              void* d_out, int out_size, void* d_ws, size_t ws_size,
                              hipStream_t stream) {
    const float* x        = (const float*)d_in[0];
    const float* eps      = (const float*)d_in[1];
    const float* Wx       = (const float*)d_in[2];
    const float* bx       = (const float*)d_in[3];
    const float* Wz1      = (const float*)d_in[4];
    const float* bz1      = (const float*)d_in[5];
    const float* Wz2      = (const float*)d_in[6];
    const float* bz2      = (const float*)d_in[7];
    const float* Wp_loc   = (const float*)d_in[8];
    const float* bp_loc   = (const float*)d_in[9];
    const float* Wp_scale = (const float*)d_in[10];
    const float* bp_scale = (const float*)d_in[11];
    const float* Wt_loc   = (const float*)d_in[12];
    const float* bt_loc   = (const float*)d_in[13];
    const float* W_ih     = (const float*)d_in[16];
    const float* W_hh     = (const float*)d_in[17];
    const float* b_ih     = (const float*)d_in[18];
    const float* b_hh     = (const float*)d_in[19];
    float* out = (float*)d_out;

    const size_t slabU = 100 * 1024;              // uints
    const size_t whnU  = 256 * 128;
    const size_t wpU   = 8 * 160;
    const size_t wtU   = 38 * 144;
    const size_t fxS   = (size_t)BN * LN * FXN;   // shorts

    uint_t* slab = (uint_t*)d_ws;
    uint_t* whnw = slab + slabU;
    uint_t* wpg  = whnw + whnU;
    uint_t* wtg  = wpg + wpU;
    ushort_t* fxbuf = (ushort_t*)(wtg + wtU);

    repack_slab<<<(int)((slabU + 255) / 256), 256, 0, stream>>>(W_ih, W_hh, slab);
    repack_whn<<<(int)((whnU + 255) / 256), 256, 0, stream>>>(W_hh, whnw);
    repack_wp<<<5, 256, 0, stream>>>(Wp_loc, Wp_scale, wpg);
    repack_wt<<<22, 256, 0, stream>>>(Wt_loc, wtg);

    if (ws_size >= (slabU + whnU + wpU + wtU) * 4 + fxS * 2) {
        fx_pre<<<BN * LN / 256, 256, 0, stream>>>(x, Wx, bx, fxbuf);
        vrnn_main<true><<<NWG, NT, 0, stream>>>(
            x, eps, Wx, bx, Wz1, bz1, Wz2, bz2, bp_loc, bp_scale, bt_loc,
            b_ih, b_hh, slab, whnw, wpg, wtg, fxbuf, out);
    } else {
        vrnn_main<false><<<NWG, NT, 0, stream>>>(
            x, eps, Wx, bx, Wz1, bz1, Wz2, bz2, bp_loc, bp_scale, bt_loc,
            b_ih, b_hh, slab, whnw, wpg, wtg, (const ushort_t*)nullptr, out);
    }
}